// Round 11
// baseline (989.709 us; speedup 1.0000x reference)
//
#include <hip/hip_runtime.h>
#include <hip/hip_cooperative_groups.h>

#define BN_EPS 1e-3f

namespace cg = cooperative_groups;

typedef __attribute__((ext_vector_type(8))) short bf16x8;
typedef __attribute__((ext_vector_type(16))) float floatx16;
typedef unsigned short u16;

__device__ __forceinline__ u16 f2bf(float f) {
  unsigned u = __float_as_uint(f);
  u += 0x7fffu + ((u >> 16) & 1u);   // RNE
  return (u16)(u >> 16);
}
__device__ __forceinline__ float bf2f(u16 h) {
  return __uint_as_float(((unsigned)h) << 16);
}

static constexpr int NSHARD = 64;   // stats shards (128 floats each)

// ---------------------------------------------------------------------------
// conv1 body (R10-verbatim, LDS carved from SM): y1[196][64] =
// im2col(x)[196][9] @ k1[9][64], hi/lo bf16 split, 3 MFMA chains,
// LDS-bounce coalesced stores.  SM usage: 32,480 B.
// ---------------------------------------------------------------------------
__device__ __forceinline__ void conv1_body(
    const float* __restrict__ x, const float* __restrict__ k1,
    u16* __restrict__ y1, float* __restrict__ statsSh, int be, char* SM)
{
  u16* smem1 = (u16*)SM;                   // 13824 u16 (Ah|Al|Wh|Wl; yS)
  float* xp = (float*)(SM + 27648);        // 30*36 floats
  float* redsum = (float*)(SM + 31968);
  float* redss  = redsum + 64;

  u16* Ah = smem1;            // [224][24]
  u16* Al = smem1 + 5376;     // [224][24]
  u16* Wh = smem1 + 10752;    // [64][24]
  u16* Wl = smem1 + 12288;    // [64][24]

  const int b = be >> 6, tid = threadIdx.x;

  {
    const uint4 z = uint4{0, 0, 0, 0};
    for (int i = tid; i < 1728; i += 256) ((uint4*)smem1)[i] = z;
    for (int i = tid; i < 270; i += 256) ((uint4*)xp)[i] = z;
    if (tid < 64) { redsum[tid] = 0.f; redss[tid] = 0.f; }
  }
  __syncthreads();

  for (int i = tid; i < 784; i += 256) {
    const int r = i / 28, c = i - 28 * r;
    xp[(r + 1) * 36 + (c + 1)] = x[(size_t)be * 784 + i];
  }
  for (int idx = tid; idx < 576; idx += 256) {
    const int t = idx >> 6, c = idx & 63;
    const float v = k1[(size_t)b * 576 + idx];
    const u16 hi = f2bf(v);
    const u16 lo = f2bf(v - bf2f(hi));
    Wh[c * 24 + t] = hi;
    Wl[c * 24 + t] = lo;
  }
  __syncthreads();

  if (tid < 196) {
    const int oy = tid / 14, ox = tid - 14 * oy;
    const float* base = &xp[(2 * oy) * 36 + 2 * ox];
#pragma unroll
    for (int ky = 0; ky < 3; ++ky)
#pragma unroll
      for (int kx = 0; kx < 3; ++kx) {
        const float v = base[ky * 36 + kx];
        const u16 hi = f2bf(v);
        const u16 lo = f2bf(v - bf2f(hi));
        Ah[tid * 24 + ky * 3 + kx] = hi;
        Al[tid * 24 + ky * 3 + kx] = lo;
      }
  }
  __syncthreads();

  const int wave = tid >> 6, lane = tid & 63;
  const int l31 = lane & 31, kq = (lane >> 5) * 8;

  bf16x8 ah[2], al[2], bh[2], bl[2];
#pragma unroll
  for (int mt = 0; mt < 2; ++mt) {
    const int row = (wave * 2 + mt) * 32 + l31;   // max 223 < 224
    ah[mt] = *(const bf16x8*)&Ah[row * 24 + kq];
    al[mt] = *(const bf16x8*)&Al[row * 24 + kq];
  }
#pragma unroll
  for (int nt = 0; nt < 2; ++nt) {
    const int colB = nt * 32 + l31;
    bh[nt] = *(const bf16x8*)&Wh[colB * 24 + kq];
    bl[nt] = *(const bf16x8*)&Wl[colB * 24 + kq];
  }

  floatx16 acc[2][2];
#pragma unroll
  for (int mt = 0; mt < 2; ++mt)
#pragma unroll
    for (int nt = 0; nt < 2; ++nt) {
#pragma unroll
      for (int r = 0; r < 16; ++r) acc[mt][nt][r] = 0.f;
      acc[mt][nt] = __builtin_amdgcn_mfma_f32_32x32x16_bf16(
          al[mt], bh[nt], acc[mt][nt], 0, 0, 0);
      acc[mt][nt] = __builtin_amdgcn_mfma_f32_32x32x16_bf16(
          ah[mt], bl[nt], acc[mt][nt], 0, 0, 0);
      acc[mt][nt] = __builtin_amdgcn_mfma_f32_32x32x16_bf16(
          ah[mt], bh[nt], acc[mt][nt], 0, 0, 0);
    }

  __syncthreads();   // fragment reads done -> smem1 reusable as yS
  u16* yS = smem1;   // [196][64] bf16

#pragma unroll
  for (int nt = 0; nt < 2; ++nt) {
    const int col = nt * 32 + l31;
    float ls = 0.f, lss = 0.f;
#pragma unroll
    for (int mt = 0; mt < 2; ++mt) {
      const int rb = (wave * 2 + mt) * 32 + 4 * (lane >> 5);
#pragma unroll
      for (int r = 0; r < 16; ++r) {
        const int rw = rb + (r & 3) + 8 * (r >> 2);
        if (rw < 196) {
          const float v = fmaxf(acc[mt][nt][r], 0.f);
          yS[rw * 64 + col] = f2bf(v);
          ls += v;
          lss = fmaf(v, v, lss);
        }
      }
    }
    atomicAdd(&redsum[col], ls);
    atomicAdd(&redss[col], lss);
  }
  __syncthreads();

  {
    uint4* dst = (uint4*)(y1 + (size_t)be * 12544);
    const uint4* s4 = (const uint4*)yS;
    for (int i = tid; i < 1568; i += 256) dst[i] = s4[i];
  }
  if (tid < 64) {
    const int sh = be & (NSHARD - 1);
    atomicAdd(&statsSh[sh * 128 + tid], redsum[tid]);
    atomicAdd(&statsSh[sh * 128 + 64 + tid], redss[tid]);
  }
  __syncthreads();   // safe LDS reuse on next grid-stride iteration
}

// ---------------------------------------------------------------------------
// foldw body (verbatim math): reduce stats shards -> s,t; emit Wf bf16
// scaled by s_cin; accumulate 9-class boundary bias.  SM usage: 19,200 B.
// ---------------------------------------------------------------------------
__device__ __forceinline__ void foldw_body(
    const float* __restrict__ W, const float* __restrict__ statsSh,
    float invN, u16* __restrict__ Wf, float* __restrict__ biasCls,
    int b, int sg, char* SM)
{
  float* T   = (float*)SM;              // [64*68]
  float* P   = (float*)(SM + 17408);    // [256]
  float* s1  = (float*)(SM + 18432);
  float* t1  = (float*)(SM + 18688);
  float* tbS = (float*)(SM + 18944);

  const int tid = threadIdx.x;

  {
    const int g = tid >> 7, cidx = tid & 127;
    float acc = 0.f;
    for (int k = 0; k < NSHARD / 2; ++k)
      acc += statsSh[(g * (NSHARD / 2) + k) * 128 + cidx];
    P[tid] = acc;
  }
  __syncthreads();
  if (tid < 64) {
    const float m = (P[tid] + P[tid + 128]) * invN;
    const float var = fmaf(-m, m, (P[64 + tid] + P[192 + tid]) * invN);
    const float s = rsqrtf(var + BN_EPS);
    s1[tid] = s;
    t1[tid] = -m * s;
  }
  __syncthreads();

  const int cin = tid >> 2, q0 = (tid & 3) * 16;
  const int cout = tid >> 2, ci0 = (tid & 3) * 16;
  for (int s = sg * 3; s < sg * 3 + 3; ++s) {
    if (tid < 64) tbS[tid] = 0.f;
    const float* ss = W + ((size_t)b * 9 + s) * 4096;
#pragma unroll
    for (int q = 0; q < 16; q += 4) {
      const float4 v = *(const float4*)(ss + cin * 64 + q0 + q);
      T[(q0 + q + 0) * 68 + cin] = v.x;
      T[(q0 + q + 1) * 68 + cin] = v.y;
      T[(q0 + q + 2) * 68 + cin] = v.z;
      T[(q0 + q + 3) * 68 + cin] = v.w;
    }
    __syncthreads();
    alignas(16) u16 tmp[16];
    float tb = 0.f;
#pragma unroll
    for (int j = 0; j < 16; ++j) {
      const float wv = T[cout * 68 + ci0 + j];
      tmp[j] = f2bf(wv * s1[ci0 + j]);
      tb = fmaf(t1[ci0 + j], wv, tb);
    }
    u16* dst = Wf + ((size_t)b * 9 + s) * 4096 + cout * 64 + ci0;
    *(uint4*)dst       = *(uint4*)&tmp[0];
    *(uint4*)(dst + 8) = *(uint4*)&tmp[8];
    atomicAdd(&tbS[cout], tb);
    __syncthreads();
    if (tid < 64) {
      const int ky = s / 3, kx = s % 3;
      const float tv = tbS[tid];
#pragma unroll
      for (int cls = 0; cls < 9; ++cls) {
        const int ry = cls / 3, rx = cls % 3;
        const bool valid = !((ry == 1 && ky == 0) || (ry == 2 && ky == 2) ||
                             (rx == 1 && kx == 0) || (rx == 2 && kx == 2));
        if (valid) atomicAdd(&biasCls[(size_t)b * 576 + cls * 64 + tid], tv);
      }
    }
    __syncthreads();
  }
}

// ---------------------------------------------------------------------------
// conv body (R9/R10-config, verbatim): stride-72 map, B2 single buffer
// fragment-major, barrier pair per slice.  SM usage: MS*144 + 11,008 B.
// ---------------------------------------------------------------------------
template <int Hin, int Hout, int G>
__device__ __forceinline__ void conv_body(
    const u16* __restrict__ yin, const u16* __restrict__ Wf,
    const float* __restrict__ biasCls, u16* __restrict__ yout,
    float* __restrict__ statsSh, int blk, char* SM)
{
  constexpr int PPI  = Hout * Hout;
  constexpr int ROWS = G * PPI;          // <= 64
  constexpr int BPT  = 64 / G;
  constexpr int MR   = G * Hin * Hin;    // map rows
  constexpr int ZR   = MR;               // zero row index
  constexpr int MS   = MR + 1;

  u16* mapS = (u16*)SM;                            // [MS][72]
  u16* B2   = (u16*)(SM + MS * 144);               // [8][64][8]
  float* biasS  = (float*)(SM + MS * 144 + 8192);  // [576]
  float* redsum = (float*)(SM + MS * 144 + 10496);
  float* redss  = redsum + 64;

  const int b = blk / BPT, e0 = (blk % BPT) * G;
  const int tid = threadIdx.x, lane = tid & 63, wave = tid >> 6;

  for (int i = tid; i < 576; i += 256) biasS[i] = biasCls[(size_t)b * 576 + i];
  if (tid < 64) { redsum[tid] = 0.f; redss[tid] = 0.f; }
  if (tid < 8) *(uint4*)&mapS[ZR * 72 + tid * 8] = uint4{0, 0, 0, 0};

  {
    const u16* src = yin + (size_t)(b * 64 + e0) * (Hin * Hin) * 64;
    for (int ch = tid; ch < MR * 8; ch += 256) {
      const int r = ch >> 3, c8 = ch & 7;
      *(uint4*)&mapS[r * 72 + c8 * 8] = *(const uint4*)(src + ch * 8);
    }
  }

  const int bco = tid >> 2, bq0 = (tid & 3) * 16, c8a = bq0 >> 3;
  const u16* wb = Wf + (size_t)b * 9 * 4096 + bco * 64 + bq0;
  {
    uint4 b0 = *(const uint4*)wb;
    uint4 b1 = *(const uint4*)(wb + 8);
    *(uint4*)&B2[((c8a + 0) * 64 + bco) * 8] = b0;
    *(uint4*)&B2[((c8a + 1) * 64 + bco) * 8] = b1;
  }

  const int m0 = (wave & 1) * 32, n0 = (wave >> 1) * 32;
  const int l31 = lane & 31, kh = lane >> 5;
  const int lrow = m0 + l31;
  const bool rv = lrow < ROWS;
  const int img = rv ? lrow / PPI : 0;
  const int pp  = rv ? lrow % PPI : 0;
  const int oy = pp / Hout, ox = pp % Hout;
  const int bcol = n0 + l31;

  floatx16 acc;
#pragma unroll
  for (int r = 0; r < 16; ++r) acc[r] = 0.f;

  __syncthreads();

#pragma unroll
  for (int s = 0; s < 9; ++s) {
    uint4 nb0, nb1;
    if (s < 8) {
      const u16* wsl = wb + (s + 1) * 4096;
      nb0 = *(const uint4*)wsl;
      nb1 = *(const uint4*)(wsl + 8);
    }
    const int ky = s / 3, kx = s % 3;
    int pix = ZR;
    if (rv) {
      const int iy = 2 * oy - 1 + ky, ix = 2 * ox - 1 + kx;
      if ((unsigned)iy < (unsigned)Hin && (unsigned)ix < (unsigned)Hin)
        pix = img * (Hin * Hin) + iy * Hin + ix;
    }
    const u16* ap = &mapS[pix * 72 + kh * 8];
    bf16x8 a[4], bv[4];
#pragma unroll
    for (int kk = 0; kk < 4; ++kk) {
      a[kk]  = *(const bf16x8*)(ap + kk * 16);
      bv[kk] = *(const bf16x8*)&B2[((((kk << 1) | kh)) * 64 + bcol) * 8];
    }
#pragma unroll
    for (int kk = 0; kk < 4; ++kk)
      acc = __builtin_amdgcn_mfma_f32_32x32x16_bf16(a[kk], bv[kk], acc, 0, 0, 0);
    if (s < 8) {
      __syncthreads();
      *(uint4*)&B2[((c8a + 0) * 64 + bco) * 8] = nb0;
      *(uint4*)&B2[((c8a + 1) * 64 + bco) * 8] = nb1;
      __syncthreads();
    }
  }

  const int col = bcol;
  const int rb = m0 + 4 * (lane >> 5);
  float ls = 0.f, lss = 0.f;
#pragma unroll
  for (int r = 0; r < 16; ++r) {
    const int rw = rb + (r & 3) + 8 * (r >> 2);
    if (rw < ROWS) {
      const int re = rw / PPI, pr = rw % PPI;
      const int ooy = pr / Hout, oox = pr % Hout;
      const int ry = (ooy == 0) ? 1 : ((2 * ooy + 1 >= Hin) ? 2 : 0);
      const int rx = (oox == 0) ? 1 : ((2 * oox + 1 >= Hin) ? 2 : 0);
      const float v = fmaxf(acc[r] + biasS[(ry * 3 + rx) * 64 + col], 0.f);
      yout[((size_t)(b * 64 + e0 + re) * PPI + pr) * 64 + col] = f2bf(v);
      ls += v;
      lss = fmaf(v, v, lss);
    }
  }
  atomicAdd(&redsum[col], ls);
  atomicAdd(&redss[col], lss);
  __syncthreads();
  if (tid < 64) {
    const int sh = blk & (NSHARD - 1);
    atomicAdd(&statsSh[sh * 128 + tid], redsum[tid]);
    atomicAdd(&statsSh[sh * 128 + 64 + tid], redss[tid]);
  }
  __syncthreads();   // safe LDS reuse on next grid-stride iteration
}

// ---------------------------------------------------------------------------
// readout body (verbatim): feat = BN(maxpool(y4)), out = feat @ w_ro[b].
// SM usage: 23,040 B.
// ---------------------------------------------------------------------------
__device__ __forceinline__ void readout_body(
    const u16* __restrict__ y4, const float* __restrict__ w_ro,
    const float* __restrict__ statsSh, float invN, float* __restrict__ outp,
    int b, char* SM)
{
  float* wl   = (float*)SM;               // [64*20]
  float* feat = (float*)(SM + 5120);      // [64*64]
  float* P    = (float*)(SM + 21504);     // [256]
  float* sArr = (float*)(SM + 22528);
  float* tArr = (float*)(SM + 22784);

  const int tid = threadIdx.x;

  {
    const int g = tid >> 7, cidx = tid & 127;
    float acc = 0.f;
    for (int k = 0; k < NSHARD / 2; ++k)
      acc += statsSh[(g * (NSHARD / 2) + k) * 128 + cidx];
    P[tid] = acc;
  }
  for (int i = tid; i < 1280; i += 256) wl[i] = w_ro[(size_t)b * 1280 + i];
  __syncthreads();
  if (tid < 64) {
    const float m = (P[tid] + P[tid + 128]) * invN;
    const float var = fmaf(-m, m, (P[64 + tid] + P[192 + tid]) * invN);
    const float s = rsqrtf(var + BN_EPS);
    sArr[tid] = s;
    tArr[tid] = -m * s;
  }
  __syncthreads();

  {
    const int e = tid & 63;
    for (int c = tid >> 6; c < 64; c += 4) {
      const u16* p4 = y4 + ((size_t)(b * 64 + e) * 4) * 64 + c;
      const float v = fmaxf(fmaxf(bf2f(p4[0]), bf2f(p4[64])),
                            fmaxf(bf2f(p4[128]), bf2f(p4[192])));
      feat[c * 64 + e] = fmaf(v, sArr[c], tArr[c]);
    }
  }
  __syncthreads();

  const int e = tid >> 2, og = (tid & 3) * 5;
  float acc[5] = {0.f, 0.f, 0.f, 0.f, 0.f};
  for (int c = 0; c < 64; ++c) {
    const float f = feat[c * 64 + e];
#pragma unroll
    for (int j = 0; j < 5; ++j) acc[j] = fmaf(f, wl[c * 20 + og + j], acc[j]);
  }
#pragma unroll
  for (int j = 0; j < 5; ++j)
    outp[((size_t)b * 64 + e) * 20 + og + j] = acc[j];
}

// ---------------------------------------------------------------------------
// pipe_k: the whole pipeline as ONE cooperative persistent kernel.
// grid.sync() replaces 7 stream boundaries (R6's hand-rolled spin storm is
// avoided — cooperative barrier is the sanctioned load-spin mechanism).
// LDS union = 39,424 B -> 4 blocks/CU co-resident.  cg4 runs G=8 (fits the
// union; per-output math bit-identical to G=16).
// ---------------------------------------------------------------------------
__global__ __launch_bounds__(256, 4) void pipe_k(
    const float* __restrict__ x,  const float* __restrict__ k1,
    const float* __restrict__ k2, const float* __restrict__ k3,
    const float* __restrict__ k4, const float* __restrict__ wro,
    float* __restrict__ out, float* __restrict__ stats,
    float* __restrict__ bias2, float* __restrict__ bias3,
    float* __restrict__ bias4, u16* __restrict__ k2f,
    u16* __restrict__ k3f, u16* __restrict__ k4f,
    u16* __restrict__ y1, u16* __restrict__ y2,
    u16* __restrict__ y3, u16* __restrict__ y4, int NG)
{
  __shared__ __align__(16) char SM[39424];
  cg::grid_group grid = cg::this_grid();
  const int bid = blockIdx.x;

  float* st1 = stats;
  float* st2 = stats + 8192;
  float* st3 = stats + 16384;
  float* st4 = stats + 24576;

  for (int be = bid; be < 4096; be += NG) conv1_body(x, k1, y1, st1, be, SM);
  __threadfence(); grid.sync();

  for (int i = bid; i < 192; i += NG)
    foldw_body(k2, st1, 1.f / 802816.f, k2f, bias2, i / 3, i % 3, SM);
  __threadfence(); grid.sync();

  for (int blk = bid; blk < 4096; blk += NG)
    conv_body<14, 7, 1>(y1, k2f, bias2, y2, st2, blk, SM);
  __threadfence(); grid.sync();

  for (int i = bid; i < 192; i += NG)
    foldw_body(k3, st2, 1.f / 200704.f, k3f, bias3, i / 3, i % 3, SM);
  __threadfence(); grid.sync();

  for (int blk = bid; blk < 1024; blk += NG)
    conv_body<7, 4, 4>(y2, k3f, bias3, y3, st3, blk, SM);
  __threadfence(); grid.sync();

  for (int i = bid; i < 192; i += NG)
    foldw_body(k4, st3, 1.f / 65536.f, k4f, bias4, i / 3, i % 3, SM);
  __threadfence(); grid.sync();

  for (int blk = bid; blk < 512; blk += NG)
    conv_body<4, 2, 8>(y3, k4f, bias4, y4, st4, blk, SM);
  __threadfence(); grid.sync();

  for (int i = bid; i < 64; i += NG)
    readout_body(y4, wro, st4, 1.f / 16384.f, out, i, SM);
}

// ---------------------------------------------------------------------------
extern "C" void kernel_launch(void* const* d_in, const int* in_sizes, int n_in,
                              void* d_out, int out_size, void* d_ws, size_t ws_size,
                              hipStream_t stream) {
  (void)in_sizes; (void)n_in; (void)out_size; (void)ws_size;
  const float* x   = (const float*)d_in[0];
  const float* k1  = (const float*)d_in[1];
  const float* k2  = (const float*)d_in[2];
  const float* k3  = (const float*)d_in[3];
  const float* k4  = (const float*)d_in[4];
  const float* wro = (const float*)d_in[5];
  float* out = (float*)d_out;
  char* ws = (char*)d_ws;

  float* stats = (float*)ws;
  float* bias2 = (float*)(ws + 131072);
  float* bias3 = bias2 + 36864;
  float* bias4 = bias3 + 36864;
  u16* k2f = (u16*)(ws + 131072 + 442368);
  u16* k3f = k2f + (size_t)2359296;
  u16* k4f = k3f + (size_t)2359296;
  u16* y2 = k4f + (size_t)2359296;
  u16* y1 = y2 + (size_t)12845056;
  u16* y3 = y1;                      // alias: y1 dead after conv2 stage
  u16* y4 = y3 + (size_t)4194304;

  hipMemsetAsync(stats, 0, 131072 + 442368, stream);

  int nb = 0;
  if (hipOccupancyMaxActiveBlocksPerMultiprocessor(&nb, pipe_k, 256, 0)
          != hipSuccess || nb < 1)
    nb = 1;
  int NG = nb * 256;                 // 256 CUs on MI355X
  if (NG > 1024) NG = 1024;          // stage loops need no more

  void* args[] = {
      (void*)&x, (void*)&k1, (void*)&k2, (void*)&k3, (void*)&k4, (void*)&wro,
      (void*)&out, (void*)&stats, (void*)&bias2, (void*)&bias3, (void*)&bias4,
      (void*)&k2f, (void*)&k3f, (void*)&k4f,
      (void*)&y1, (void*)&y2, (void*)&y3, (void*)&y4, (void*)&NG};
  hipLaunchCooperativeKernel(pipe_k, dim3(NG), dim3(256), args, 0, stream);
}

// Round 12
// 335.502 us; speedup vs baseline: 2.9499x; 2.9499x over previous
//
#include <hip/hip_runtime.h>

#define BN_EPS 1e-3f

typedef __attribute__((ext_vector_type(8))) short bf16x8;
typedef __attribute__((ext_vector_type(16))) float floatx16;
typedef unsigned short u16;

__device__ __forceinline__ u16 f2bf(float f) {
  unsigned u = __float_as_uint(f);
  u += 0x7fffu + ((u >> 16) & 1u);   // RNE
  return (u16)(u >> 16);
}
__device__ __forceinline__ float bf2f(u16 h) {
  return __uint_as_float(((unsigned)h) << 16);
}

static constexpr int NSHARD = 64;   // stats shards (128 floats each)

// ---------------------------------------------------------------------------
// conv1 via MFMA (R10-proven, 5 blocks/CU): y1[196][64] =
// im2col(x)[196][9] @ k1[9][64], hi/lo bf16 split, 3 MFMA chains,
// LDS-bounce coalesced stores.
// ---------------------------------------------------------------------------
__global__ __launch_bounds__(256, 5) void conv1_k(
    const float* __restrict__ x, const float* __restrict__ k1,
    u16* __restrict__ y1, float* __restrict__ statsSh)
{
  __shared__ __align__(16) u16 smem1[13824];  // Ah|Al|Wh|Wl; reused as yS
  __shared__ __align__(16) float xp[30 * 36]; // zero border, stride 36
  __shared__ float redsum[64], redss[64];

  u16* Ah = smem1;            // [224][24]
  u16* Al = smem1 + 5376;     // [224][24]
  u16* Wh = smem1 + 10752;    // [64][24]
  u16* Wl = smem1 + 12288;    // [64][24]

  const int be = blockIdx.x, b = be >> 6, tid = threadIdx.x;

  {
    const uint4 z = uint4{0, 0, 0, 0};
    for (int i = tid; i < 1728; i += 256) ((uint4*)smem1)[i] = z;
    for (int i = tid; i < 270; i += 256) ((uint4*)xp)[i] = z;
    if (tid < 64) { redsum[tid] = 0.f; redss[tid] = 0.f; }
  }
  __syncthreads();

  for (int i = tid; i < 784; i += 256) {
    const int r = i / 28, c = i - 28 * r;
    xp[(r + 1) * 36 + (c + 1)] = x[(size_t)be * 784 + i];
  }
  for (int idx = tid; idx < 576; idx += 256) {
    const int t = idx >> 6, c = idx & 63;
    const float v = k1[(size_t)b * 576 + idx];
    const u16 hi = f2bf(v);
    const u16 lo = f2bf(v - bf2f(hi));
    Wh[c * 24 + t] = hi;
    Wl[c * 24 + t] = lo;
  }
  __syncthreads();

  if (tid < 196) {
    const int oy = tid / 14, ox = tid - 14 * oy;
    const float* base = &xp[(2 * oy) * 36 + 2 * ox];
#pragma unroll
    for (int ky = 0; ky < 3; ++ky)
#pragma unroll
      for (int kx = 0; kx < 3; ++kx) {
        const float v = base[ky * 36 + kx];
        const u16 hi = f2bf(v);
        const u16 lo = f2bf(v - bf2f(hi));
        Ah[tid * 24 + ky * 3 + kx] = hi;
        Al[tid * 24 + ky * 3 + kx] = lo;
      }
  }
  __syncthreads();

  const int wave = tid >> 6, lane = tid & 63;
  const int l31 = lane & 31, kq = (lane >> 5) * 8;

  bf16x8 ah[2], al[2], bh[2], bl[2];
#pragma unroll
  for (int mt = 0; mt < 2; ++mt) {
    const int row = (wave * 2 + mt) * 32 + l31;   // max 223 < 224
    ah[mt] = *(const bf16x8*)&Ah[row * 24 + kq];
    al[mt] = *(const bf16x8*)&Al[row * 24 + kq];
  }
#pragma unroll
  for (int nt = 0; nt < 2; ++nt) {
    const int colB = nt * 32 + l31;
    bh[nt] = *(const bf16x8*)&Wh[colB * 24 + kq];
    bl[nt] = *(const bf16x8*)&Wl[colB * 24 + kq];
  }

  floatx16 acc[2][2];
#pragma unroll
  for (int mt = 0; mt < 2; ++mt)
#pragma unroll
    for (int nt = 0; nt < 2; ++nt) {
#pragma unroll
      for (int r = 0; r < 16; ++r) acc[mt][nt][r] = 0.f;
      acc[mt][nt] = __builtin_amdgcn_mfma_f32_32x32x16_bf16(
          al[mt], bh[nt], acc[mt][nt], 0, 0, 0);
      acc[mt][nt] = __builtin_amdgcn_mfma_f32_32x32x16_bf16(
          ah[mt], bl[nt], acc[mt][nt], 0, 0, 0);
      acc[mt][nt] = __builtin_amdgcn_mfma_f32_32x32x16_bf16(
          ah[mt], bh[nt], acc[mt][nt], 0, 0, 0);
    }

  __syncthreads();   // fragment reads done -> smem1 reusable as yS
  u16* yS = smem1;   // [196][64] bf16

#pragma unroll
  for (int nt = 0; nt < 2; ++nt) {
    const int col = nt * 32 + l31;
    float ls = 0.f, lss = 0.f;
#pragma unroll
    for (int mt = 0; mt < 2; ++mt) {
      const int rb = (wave * 2 + mt) * 32 + 4 * (lane >> 5);
#pragma unroll
      for (int r = 0; r < 16; ++r) {
        const int rw = rb + (r & 3) + 8 * (r >> 2);
        if (rw < 196) {
          const float v = fmaxf(acc[mt][nt][r], 0.f);
          yS[rw * 64 + col] = f2bf(v);
          ls += v;
          lss = fmaf(v, v, lss);
        }
      }
    }
    atomicAdd(&redsum[col], ls);
    atomicAdd(&redss[col], lss);
  }
  __syncthreads();

  {
    uint4* dst = (uint4*)(y1 + (size_t)be * 12544);
    const uint4* s4 = (const uint4*)yS;
    for (int i = tid; i < 1568; i += 256) dst[i] = s4[i];
  }
  if (tid < 64) {
    const int sh = be & (NSHARD - 1);
    atomicAdd(&statsSh[sh * 128 + tid], redsum[tid]);
    atomicAdd(&statsSh[sh * 128 + 64 + tid], redss[tid]);
  }
}

// ---------------------------------------------------------------------------
// fold: block (task, slice-triple).  Reduce stats shards -> s,t; emit
// Wf bf16 [b][s][cout][cin] scaled by s_cin; accumulate 9-class boundary
// bias table bias[b][cls][cout] (zeroed by memset).  Separate launch —
// R6/R11 proved any device-side cross-block sync is catastrophic here.
// ---------------------------------------------------------------------------
__global__ __launch_bounds__(256) void foldw_k(
    const float* __restrict__ W, const float* __restrict__ statsSh, float invN,
    u16* __restrict__ Wf, float* __restrict__ biasCls)
{
  __shared__ float T[64 * 68];
  __shared__ float P[256];
  __shared__ float s1[64], t1[64];
  __shared__ float tbS[64];

  const int b = blockIdx.x / 3, sg = blockIdx.x % 3;
  const int tid = threadIdx.x;

  {
    const int g = tid >> 7, cidx = tid & 127;
    float acc = 0.f;
    for (int k = 0; k < NSHARD / 2; ++k)
      acc += statsSh[(g * (NSHARD / 2) + k) * 128 + cidx];
    P[tid] = acc;
  }
  __syncthreads();
  if (tid < 64) {
    const float m = (P[tid] + P[tid + 128]) * invN;
    const float var = fmaf(-m, m, (P[64 + tid] + P[192 + tid]) * invN);
    const float s = rsqrtf(var + BN_EPS);
    s1[tid] = s;
    t1[tid] = -m * s;
  }
  __syncthreads();

  const int cin = tid >> 2, q0 = (tid & 3) * 16;
  const int cout = tid >> 2, ci0 = (tid & 3) * 16;
  for (int s = sg * 3; s < sg * 3 + 3; ++s) {
    if (tid < 64) tbS[tid] = 0.f;
    const float* ss = W + ((size_t)b * 9 + s) * 4096;
#pragma unroll
    for (int q = 0; q < 16; q += 4) {
      const float4 v = *(const float4*)(ss + cin * 64 + q0 + q);
      T[(q0 + q + 0) * 68 + cin] = v.x;
      T[(q0 + q + 1) * 68 + cin] = v.y;
      T[(q0 + q + 2) * 68 + cin] = v.z;
      T[(q0 + q + 3) * 68 + cin] = v.w;
    }
    __syncthreads();
    alignas(16) u16 tmp[16];
    float tb = 0.f;
#pragma unroll
    for (int j = 0; j < 16; ++j) {
      const float wv = T[cout * 68 + ci0 + j];
      tmp[j] = f2bf(wv * s1[ci0 + j]);
      tb = fmaf(t1[ci0 + j], wv, tb);
    }
    u16* dst = Wf + ((size_t)b * 9 + s) * 4096 + cout * 64 + ci0;
    *(uint4*)dst       = *(uint4*)&tmp[0];
    *(uint4*)(dst + 8) = *(uint4*)&tmp[8];
    atomicAdd(&tbS[cout], tb);
    __syncthreads();
    if (tid < 64) {
      const int ky = s / 3, kx = s % 3;
      const float tv = tbS[tid];
#pragma unroll
      for (int cls = 0; cls < 9; ++cls) {
        const int ry = cls / 3, rx = cls % 3;
        const bool valid = !((ry == 1 && ky == 0) || (ry == 2 && ky == 2) ||
                             (rx == 1 && kx == 0) || (rx == 2 && kx == 2));
        if (valid) atomicAdd(&biasCls[(size_t)b * 576 + cls * 64 + tid], tv);
      }
    }
    __syncthreads();
  }
}

// ---------------------------------------------------------------------------
// conv_core v8: R9/R10 structure (stride-72 map, B2 single buffer
// fragment-major, barrier pair per slice) with ONE change: ALL 8 remaining
// B-slice loads are hoisted into registers (nb[8][2], 64 VGPRs,
// constant-indexed after full unroll, pinned with sched_barrier) BEFORE
// the K-loop.  The per-slice vmcnt(0) drain at the barriers then costs
// nothing after slice 0 — removing ~200-400 cyc of exposed L2 latency
// per slice per wave.  Arithmetic order unchanged.
// ---------------------------------------------------------------------------
template <int Hin, int Hout, int G>
__device__ __forceinline__ void conv_core(
    const u16* __restrict__ yin, const u16* __restrict__ Wf,
    const float* __restrict__ biasCls, u16* __restrict__ yout,
    float* __restrict__ statsSh, int blk)
{
  constexpr int PPI  = Hout * Hout;
  constexpr int ROWS = G * PPI;          // <= 64
  constexpr int BPT  = 64 / G;
  constexpr int MR   = G * Hin * Hin;    // map rows
  constexpr int ZR   = MR;               // zero row index
  constexpr int MS   = MR + 1;           // rows incl. zero row

  __shared__ __align__(16) u16 mapS[MS * 72];      // [pix][72]
  __shared__ __align__(16) u16 B2[8 * 64 * 8];     // [c8][col][8]
  __shared__ float biasS[576];
  __shared__ float redsum[64], redss[64];

  const int b = blk / BPT, e0 = (blk % BPT) * G;
  const int tid = threadIdx.x, lane = tid & 63, wave = tid >> 6;

  for (int i = tid; i < 576; i += 256) biasS[i] = biasCls[(size_t)b * 576 + i];
  if (tid < 64) { redsum[tid] = 0.f; redss[tid] = 0.f; }
  if (tid < 8) *(uint4*)&mapS[ZR * 72 + tid * 8] = uint4{0, 0, 0, 0};

  // stage the G-image group: chunk (pix=r, c8) -> mapS[r*72 + c8*8]
  {
    const u16* src = yin + (size_t)(b * 64 + e0) * (Hin * Hin) * 64;
    for (int ch = tid; ch < MR * 8; ch += 256) {
      const int r = ch >> 3, c8 = ch & 7;
      *(uint4*)&mapS[r * 72 + c8 * 8] = *(const uint4*)(src + ch * 8);
    }
  }

  // B slice 0 -> B2; slices 1..8 -> registers (hoisted, pinned)
  const int bco = tid >> 2, bq0 = (tid & 3) * 16, c8a = bq0 >> 3;
  const u16* wb = Wf + (size_t)b * 9 * 4096 + bco * 64 + bq0;
  {
    uint4 b0 = *(const uint4*)wb;
    uint4 b1 = *(const uint4*)(wb + 8);
    *(uint4*)&B2[((c8a + 0) * 64 + bco) * 8] = b0;
    *(uint4*)&B2[((c8a + 1) * 64 + bco) * 8] = b1;
  }
  uint4 nb[8][2];
#pragma unroll
  for (int s = 0; s < 8; ++s) {
    const u16* wsl = wb + (s + 1) * 4096;
    nb[s][0] = *(const uint4*)wsl;
    nb[s][1] = *(const uint4*)(wsl + 8);
  }
  __builtin_amdgcn_sched_barrier(0);   // pin the hoisted loads here

  const int m0 = (wave & 1) * 32, n0 = (wave >> 1) * 32;
  const int l31 = lane & 31, kh = lane >> 5;
  const int lrow = m0 + l31;
  const bool rv = lrow < ROWS;
  const int img = rv ? lrow / PPI : 0;
  const int pp  = rv ? lrow % PPI : 0;
  const int oy = pp / Hout, ox = pp % Hout;
  const int bcol = n0 + l31;

  floatx16 acc;
#pragma unroll
  for (int r = 0; r < 16; ++r) acc[r] = 0.f;

  __syncthreads();   // mapS + B2 slice 0 + bias visible

#pragma unroll
  for (int s = 0; s < 9; ++s) {
    const int ky = s / 3, kx = s % 3;
    int pix = ZR;
    if (rv) {
      const int iy = 2 * oy - 1 + ky, ix = 2 * ox - 1 + kx;
      if ((unsigned)iy < (unsigned)Hin && (unsigned)ix < (unsigned)Hin)
        pix = img * (Hin * Hin) + iy * Hin + ix;
    }
    const u16* ap = &mapS[pix * 72 + kh * 8];
    bf16x8 a[4], bv[4];
#pragma unroll
    for (int kk = 0; kk < 4; ++kk) {
      a[kk]  = *(const bf16x8*)(ap + kk * 16);
      bv[kk] = *(const bf16x8*)&B2[((((kk << 1) | kh)) * 64 + bcol) * 8];
    }
#pragma unroll
    for (int kk = 0; kk < 4; ++kk)
      acc = __builtin_amdgcn_mfma_f32_32x32x16_bf16(a[kk], bv[kk], acc, 0, 0, 0);
    if (s < 8) {
      __syncthreads();   // all reads of B2 slice s complete
      *(uint4*)&B2[((c8a + 0) * 64 + bco) * 8] = nb[s][0];
      *(uint4*)&B2[((c8a + 1) * 64 + bco) * 8] = nb[s][1];
      __syncthreads();   // B2 slice s+1 ready
    }
  }

  // epilogue: boundary-class bias, ReLU, bf16 store, stats
  const int col = bcol;
  const int rb = m0 + 4 * (lane >> 5);
  float ls = 0.f, lss = 0.f;
#pragma unroll
  for (int r = 0; r < 16; ++r) {
    const int rw = rb + (r & 3) + 8 * (r >> 2);
    if (rw < ROWS) {
      const int re = rw / PPI, pr = rw % PPI;
      const int ooy = pr / Hout, oox = pr % Hout;
      const int ry = (ooy == 0) ? 1 : ((2 * ooy + 1 >= Hin) ? 2 : 0);
      const int rx = (oox == 0) ? 1 : ((2 * oox + 1 >= Hin) ? 2 : 0);
      const float v = fmaxf(acc[r] + biasS[(ry * 3 + rx) * 64 + col], 0.f);
      yout[((size_t)(b * 64 + e0 + re) * PPI + pr) * 64 + col] = f2bf(v);
      ls += v;
      lss = fmaf(v, v, lss);
    }
  }
  atomicAdd(&redsum[col], ls);
  atomicAdd(&redss[col], lss);
  __syncthreads();
  if (tid < 64) {
    const int sh = blk & (NSHARD - 1);
    atomicAdd(&statsSh[sh * 128 + tid], redsum[tid]);
    atomicAdd(&statsSh[sh * 128 + 64 + tid], redss[tid]);
  }
}

__global__ __launch_bounds__(256, 4) void cg2_k(
    const u16* __restrict__ yin, const u16* __restrict__ Wf,
    const float* __restrict__ biasCls, u16* __restrict__ yout,
    float* __restrict__ statsSh) {
  conv_core<14, 7, 1>(yin, Wf, biasCls, yout, statsSh, blockIdx.x);
}
__global__ __launch_bounds__(256, 4) void cg3_k(
    const u16* __restrict__ yin, const u16* __restrict__ Wf,
    const float* __restrict__ biasCls, u16* __restrict__ yout,
    float* __restrict__ statsSh) {
  conv_core<7, 4, 4>(yin, Wf, biasCls, yout, statsSh, blockIdx.x);
}
__global__ __launch_bounds__(256, 4) void cg4_k(
    const u16* __restrict__ yin, const u16* __restrict__ Wf,
    const float* __restrict__ biasCls, u16* __restrict__ yout,
    float* __restrict__ statsSh) {
  conv_core<4, 2, 16>(yin, Wf, biasCls, yout, statsSh, blockIdx.x);
}

// ---------------------------------------------------------------------------
// readout: reduce stats4 shards, feat = BN(maxpool(y4)), out = feat @ w_ro[b].
// ---------------------------------------------------------------------------
__global__ __launch_bounds__(256) void readout_k(
    const u16* __restrict__ y4, const float* __restrict__ w_ro,
    const float* __restrict__ statsSh, float invN, float* __restrict__ outp)
{
  __shared__ float wl[64 * 20];
  __shared__ float feat[64 * 64];
  __shared__ float P[256];
  __shared__ float sArr[64], tArr[64];

  const int b = blockIdx.x, tid = threadIdx.x;

  {
    const int g = tid >> 7, cidx = tid & 127;
    float acc = 0.f;
    for (int k = 0; k < NSHARD / 2; ++k)
      acc += statsSh[(g * (NSHARD / 2) + k) * 128 + cidx];
    P[tid] = acc;
  }
  for (int i = tid; i < 1280; i += 256) wl[i] = w_ro[(size_t)b * 1280 + i];
  __syncthreads();
  if (tid < 64) {
    const float m = (P[tid] + P[tid + 128]) * invN;
    const float var = fmaf(-m, m, (P[64 + tid] + P[192 + tid]) * invN);
    const float s = rsqrtf(var + BN_EPS);
    sArr[tid] = s;
    tArr[tid] = -m * s;
  }
  __syncthreads();

  {
    const int e = tid & 63;
    for (int c = tid >> 6; c < 64; c += 4) {
      const u16* p4 = y4 + ((size_t)(b * 64 + e) * 4) * 64 + c;
      const float v = fmaxf(fmaxf(bf2f(p4[0]), bf2f(p4[64])),
                            fmaxf(bf2f(p4[128]), bf2f(p4[192])));
      feat[c * 64 + e] = fmaf(v, sArr[c], tArr[c]);
    }
  }
  __syncthreads();

  const int e = tid >> 2, og = (tid & 3) * 5;
  float acc[5] = {0.f, 0.f, 0.f, 0.f, 0.f};
  for (int c = 0; c < 64; ++c) {
    const float f = feat[c * 64 + e];
#pragma unroll
    for (int j = 0; j < 5; ++j) acc[j] = fmaf(f, wl[c * 20 + og + j], acc[j]);
  }
#pragma unroll
  for (int j = 0; j < 5; ++j)
    outp[((size_t)b * 64 + e) * 20 + og + j] = acc[j];
}

// ---------------------------------------------------------------------------
extern "C" void kernel_launch(void* const* d_in, const int* in_sizes, int n_in,
                              void* d_out, int out_size, void* d_ws, size_t ws_size,
                              hipStream_t stream) {
  (void)in_sizes; (void)n_in; (void)out_size; (void)ws_size;
  const float* x   = (const float*)d_in[0];
  const float* k1  = (const float*)d_in[1];
  const float* k2  = (const float*)d_in[2];
  const float* k3  = (const float*)d_in[3];
  const float* k4  = (const float*)d_in[4];
  const float* wro = (const float*)d_in[5];
  float* out = (float*)d_out;
  char* ws = (char*)d_ws;

  // ws layout (bytes), total ~143 MB:
  //  stats: 4 layers x 64 shards x 128 f32         = 131072
  //  bias2/3/4: 64 x 576 f32                       = 3 x 147456  (memset w/ stats)
  //  k2f/k3f/k4f bf16                              = 3 x 4718592
  //  y2 bf16 [4096][49][64]                        = 25690112
  //  y1 bf16 [4096][196][64]                       = 102760448 (y3/y4 alias in)
  float* stats = (float*)ws;
  float* bias2 = (float*)(ws + 131072);
  float* bias3 = bias2 + 36864;
  float* bias4 = bias3 + 36864;
  u16* k2f = (u16*)(ws + 131072 + 442368);
  u16* k3f = k2f + (size_t)2359296;
  u16* k4f = k3f + (size_t)2359296;
  u16* y2 = k4f + (size_t)2359296;
  u16* y1 = y2 + (size_t)12845056;
  u16* y3 = y1;                      // alias: y1 dead after conv2
  u16* y4 = y3 + (size_t)4194304;

  float* st1 = stats;
  float* st2 = stats + 8192;
  float* st3 = stats + 16384;
  float* st4 = stats + 24576;

  hipMemsetAsync(stats, 0, 131072 + 442368, stream);

  conv1_k<<<4096, 256, 0, stream>>>(x, k1, y1, st1);
  foldw_k<<<192, 256, 0, stream>>>(k2, st1, 1.f / 802816.f, k2f, bias2);
  cg2_k<<<4096, 256, 0, stream>>>(y1, k2f, bias2, y2, st2);
  foldw_k<<<192, 256, 0, stream>>>(k3, st2, 1.f / 200704.f, k3f, bias3);
  cg3_k<<<1024, 256, 0, stream>>>(y2, k3f, bias3, y3, st3);
  foldw_k<<<192, 256, 0, stream>>>(k4, st3, 1.f / 65536.f, k4f, bias4);
  cg4_k<<<256, 256, 0, stream>>>(y3, k4f, bias4, y4, st4);
  readout_k<<<64, 256, 0, stream>>>(y4, wro, st4, 1.f / 16384.f, out);
}

// Round 13
// 252.139 us; speedup vs baseline: 3.9253x; 1.3306x over previous
//
#include <hip/hip_runtime.h>

#define BN_EPS 1e-3f

typedef __attribute__((ext_vector_type(8))) short bf16x8;
typedef __attribute__((ext_vector_type(16))) float floatx16;
typedef unsigned short u16;

__device__ __forceinline__ u16 f2bf(float f) {
  unsigned u = __float_as_uint(f);
  u += 0x7fffu + ((u >> 16) & 1u);   // RNE
  return (u16)(u >> 16);
}
__device__ __forceinline__ float bf2f(u16 h) {
  return __uint_as_float(((unsigned)h) << 16);
}

static constexpr int NSHARD = 64;   // stats shards (128 floats each)

// ---------------------------------------------------------------------------
// conv1 via MFMA: y1[196][64] = im2col(x)[196][9] @ k1[9][64], hi/lo bf16
// split, 3 MFMA chains; LDS-bounce coalesced stores.  A-buffers 224 rows
// (rows >=196 never stored; max row read = 223).  32.48 KB -> 5 blocks/CU.
// ---------------------------------------------------------------------------
__global__ __launch_bounds__(256, 5) void conv1_k(
    const float* __restrict__ x, const float* __restrict__ k1,
    u16* __restrict__ y1, float* __restrict__ statsSh)
{
  __shared__ __align__(16) u16 smem1[13824];  // Ah|Al|Wh|Wl; reused as yS
  __shared__ __align__(16) float xp[30 * 36]; // zero border, stride 36
  __shared__ float redsum[64], redss[64];

  u16* Ah = smem1;            // [224][24]
  u16* Al = smem1 + 5376;     // [224][24]
  u16* Wh = smem1 + 10752;    // [64][24]
  u16* Wl = smem1 + 12288;    // [64][24]

  const int be = blockIdx.x, b = be >> 6, tid = threadIdx.x;

  {
    const uint4 z = uint4{0, 0, 0, 0};
    for (int i = tid; i < 1728; i += 256) ((uint4*)smem1)[i] = z;
    for (int i = tid; i < 270; i += 256) ((uint4*)xp)[i] = z;
    if (tid < 64) { redsum[tid] = 0.f; redss[tid] = 0.f; }
  }
  __syncthreads();

  for (int i = tid; i < 784; i += 256) {
    const int r = i / 28, c = i - 28 * r;
    xp[(r + 1) * 36 + (c + 1)] = x[(size_t)be * 784 + i];
  }
  for (int idx = tid; idx < 576; idx += 256) {
    const int t = idx >> 6, c = idx & 63;
    const float v = k1[(size_t)b * 576 + idx];
    const u16 hi = f2bf(v);
    const u16 lo = f2bf(v - bf2f(hi));
    Wh[c * 24 + t] = hi;
    Wl[c * 24 + t] = lo;
  }
  __syncthreads();

  if (tid < 196) {
    const int oy = tid / 14, ox = tid - 14 * oy;
    const float* base = &xp[(2 * oy) * 36 + 2 * ox];
#pragma unroll
    for (int ky = 0; ky < 3; ++ky)
#pragma unroll
      for (int kx = 0; kx < 3; ++kx) {
        const float v = base[ky * 36 + kx];
        const u16 hi = f2bf(v);
        const u16 lo = f2bf(v - bf2f(hi));
        Ah[tid * 24 + ky * 3 + kx] = hi;
        Al[tid * 24 + ky * 3 + kx] = lo;
      }
  }
  __syncthreads();

  const int wave = tid >> 6, lane = tid & 63;
  const int l31 = lane & 31, kq = (lane >> 5) * 8;

  bf16x8 ah[2], al[2], bh[2], bl[2];
#pragma unroll
  for (int mt = 0; mt < 2; ++mt) {
    const int row = (wave * 2 + mt) * 32 + l31;   // max 223 < 224
    ah[mt] = *(const bf16x8*)&Ah[row * 24 + kq];
    al[mt] = *(const bf16x8*)&Al[row * 24 + kq];
  }
#pragma unroll
  for (int nt = 0; nt < 2; ++nt) {
    const int colB = nt * 32 + l31;
    bh[nt] = *(const bf16x8*)&Wh[colB * 24 + kq];
    bl[nt] = *(const bf16x8*)&Wl[colB * 24 + kq];
  }

  floatx16 acc[2][2];
#pragma unroll
  for (int mt = 0; mt < 2; ++mt)
#pragma unroll
    for (int nt = 0; nt < 2; ++nt) {
#pragma unroll
      for (int r = 0; r < 16; ++r) acc[mt][nt][r] = 0.f;
      acc[mt][nt] = __builtin_amdgcn_mfma_f32_32x32x16_bf16(
          al[mt], bh[nt], acc[mt][nt], 0, 0, 0);
      acc[mt][nt] = __builtin_amdgcn_mfma_f32_32x32x16_bf16(
          ah[mt], bl[nt], acc[mt][nt], 0, 0, 0);
      acc[mt][nt] = __builtin_amdgcn_mfma_f32_32x32x16_bf16(
          ah[mt], bh[nt], acc[mt][nt], 0, 0, 0);
    }

  __syncthreads();   // all LDS fragment reads done -> smem1 reusable as yS
  u16* yS = smem1;   // [196][64] bf16, row-major (12544 u16 <= 13824)

#pragma unroll
  for (int nt = 0; nt < 2; ++nt) {
    const int col = nt * 32 + l31;
    float ls = 0.f, lss = 0.f;
#pragma unroll
    for (int mt = 0; mt < 2; ++mt) {
      const int rb = (wave * 2 + mt) * 32 + 4 * (lane >> 5);
#pragma unroll
      for (int r = 0; r < 16; ++r) {
        const int rw = rb + (r & 3) + 8 * (r >> 2);
        if (rw < 196) {
          const float v = fmaxf(acc[mt][nt][r], 0.f);
          yS[rw * 64 + col] = f2bf(v);
          ls += v;
          lss = fmaf(v, v, lss);
        }
      }
    }
    atomicAdd(&redsum[col], ls);
    atomicAdd(&redss[col], lss);
  }
  __syncthreads();

  {
    uint4* dst = (uint4*)(y1 + (size_t)be * 12544);
    const uint4* s4 = (const uint4*)yS;
    for (int i = tid; i < 1568; i += 256) dst[i] = s4[i];
  }
  if (tid < 64) {
    const int sh = be & (NSHARD - 1);
    atomicAdd(&statsSh[sh * 128 + tid], redsum[tid]);
    atomicAdd(&statsSh[sh * 128 + 64 + tid], redss[tid]);
  }
}

// ---------------------------------------------------------------------------
// fold: block (task, slice-triple).  Reduce stats shards -> s,t; emit
// Wf bf16 [b][s][cout][cin] scaled by s_cin; accumulate 9-class boundary
// bias table bias[b][cls][cout] (zeroed by memset).  Separate launch —
// R6/R11 proved any device-side cross-block sync is catastrophic here.
// ---------------------------------------------------------------------------
__global__ __launch_bounds__(256) void foldw_k(
    const float* __restrict__ W, const float* __restrict__ statsSh, float invN,
    u16* __restrict__ Wf, float* __restrict__ biasCls)
{
  __shared__ float T[64 * 68];
  __shared__ float P[256];
  __shared__ float s1[64], t1[64];
  __shared__ float tbS[64];

  const int b = blockIdx.x / 3, sg = blockIdx.x % 3;
  const int tid = threadIdx.x;

  {
    const int g = tid >> 7, cidx = tid & 127;
    float acc = 0.f;
    for (int k = 0; k < NSHARD / 2; ++k)
      acc += statsSh[(g * (NSHARD / 2) + k) * 128 + cidx];
    P[tid] = acc;
  }
  __syncthreads();
  if (tid < 64) {
    const float m = (P[tid] + P[tid + 128]) * invN;
    const float var = fmaf(-m, m, (P[64 + tid] + P[192 + tid]) * invN);
    const float s = rsqrtf(var + BN_EPS);
    s1[tid] = s;
    t1[tid] = -m * s;
  }
  __syncthreads();

  const int cin = tid >> 2, q0 = (tid & 3) * 16;
  const int cout = tid >> 2, ci0 = (tid & 3) * 16;
  for (int s = sg * 3; s < sg * 3 + 3; ++s) {
    if (tid < 64) tbS[tid] = 0.f;
    const float* ss = W + ((size_t)b * 9 + s) * 4096;
#pragma unroll
    for (int q = 0; q < 16; q += 4) {
      const float4 v = *(const float4*)(ss + cin * 64 + q0 + q);
      T[(q0 + q + 0) * 68 + cin] = v.x;
      T[(q0 + q + 1) * 68 + cin] = v.y;
      T[(q0 + q + 2) * 68 + cin] = v.z;
      T[(q0 + q + 3) * 68 + cin] = v.w;
    }
    __syncthreads();
    alignas(16) u16 tmp[16];
    float tb = 0.f;
#pragma unroll
    for (int j = 0; j < 16; ++j) {
      const float wv = T[cout * 68 + ci0 + j];
      tmp[j] = f2bf(wv * s1[ci0 + j]);
      tb = fmaf(t1[ci0 + j], wv, tb);
    }
    u16* dst = Wf + ((size_t)b * 9 + s) * 4096 + cout * 64 + ci0;
    *(uint4*)dst       = *(uint4*)&tmp[0];
    *(uint4*)(dst + 8) = *(uint4*)&tmp[8];
    atomicAdd(&tbS[cout], tb);
    __syncthreads();
    if (tid < 64) {
      const int ky = s / 3, kx = s % 3;
      const float tv = tbS[tid];
#pragma unroll
      for (int cls = 0; cls < 9; ++cls) {
        const int ry = cls / 3, rx = cls % 3;
        const bool valid = !((ry == 1 && ky == 0) || (ry == 2 && ky == 2) ||
                             (rx == 1 && kx == 0) || (rx == 2 && kx == 2));
        if (valid) atomicAdd(&biasCls[(size_t)b * 576 + cls * 64 + tid], tv);
      }
    }
    __syncthreads();
  }
}

// ---------------------------------------------------------------------------
// conv_core (R9/R10 config, best-measured): stride-72 map, B2 single
// buffer fragment-major, barrier pair per slice, register prefetch depth 1
// (deeper prefetch scratch-demotes — R3/R12), 4 blocks/CU.
// ---------------------------------------------------------------------------
template <int Hin, int Hout, int G>
__device__ __forceinline__ void conv_core(
    const u16* __restrict__ yin, const u16* __restrict__ Wf,
    const float* __restrict__ biasCls, u16* __restrict__ yout,
    float* __restrict__ statsSh, int blk)
{
  constexpr int PPI  = Hout * Hout;
  constexpr int ROWS = G * PPI;          // <= 64
  constexpr int BPT  = 64 / G;
  constexpr int MR   = G * Hin * Hin;    // map rows
  constexpr int ZR   = MR;               // zero row index
  constexpr int MS   = MR + 1;           // rows incl. zero row

  __shared__ __align__(16) u16 mapS[MS * 72];      // [pix][72]
  __shared__ __align__(16) u16 B2[8 * 64 * 8];     // [c8][col][8]
  __shared__ float biasS[576];
  __shared__ float redsum[64], redss[64];

  const int b = blk / BPT, e0 = (blk % BPT) * G;
  const int tid = threadIdx.x, lane = tid & 63, wave = tid >> 6;

  for (int i = tid; i < 576; i += 256) biasS[i] = biasCls[(size_t)b * 576 + i];
  if (tid < 64) { redsum[tid] = 0.f; redss[tid] = 0.f; }
  if (tid < 8) *(uint4*)&mapS[ZR * 72 + tid * 8] = uint4{0, 0, 0, 0};

  // stage the G-image group: chunk (pix=r, c8) -> mapS[r*72 + c8*8]
  {
    const u16* src = yin + (size_t)(b * 64 + e0) * (Hin * Hin) * 64;
    for (int ch = tid; ch < MR * 8; ch += 256) {
      const int r = ch >> 3, c8 = ch & 7;
      *(uint4*)&mapS[r * 72 + c8 * 8] = *(const uint4*)(src + ch * 8);
    }
  }

  // B slice 0 -> B2
  const int bco = tid >> 2, bq0 = (tid & 3) * 16, c8a = bq0 >> 3;
  const u16* wb = Wf + (size_t)b * 9 * 4096 + bco * 64 + bq0;
  {
    uint4 b0 = *(const uint4*)wb;
    uint4 b1 = *(const uint4*)(wb + 8);
    *(uint4*)&B2[((c8a + 0) * 64 + bco) * 8] = b0;
    *(uint4*)&B2[((c8a + 1) * 64 + bco) * 8] = b1;
  }

  const int m0 = (wave & 1) * 32, n0 = (wave >> 1) * 32;
  const int l31 = lane & 31, kh = lane >> 5;
  const int lrow = m0 + l31;
  const bool rv = lrow < ROWS;
  const int img = rv ? lrow / PPI : 0;
  const int pp  = rv ? lrow % PPI : 0;
  const int oy = pp / Hout, ox = pp % Hout;
  const int bcol = n0 + l31;

  floatx16 acc;
#pragma unroll
  for (int r = 0; r < 16; ++r) acc[r] = 0.f;

  __syncthreads();   // mapS + B2 slice 0 + bias visible

#pragma unroll
  for (int s = 0; s < 9; ++s) {
    uint4 nb0, nb1;
    if (s < 8) {
      const u16* wsl = wb + (s + 1) * 4096;
      nb0 = *(const uint4*)wsl;
      nb1 = *(const uint4*)(wsl + 8);
    }
    const int ky = s / 3, kx = s % 3;
    int pix = ZR;
    if (rv) {
      const int iy = 2 * oy - 1 + ky, ix = 2 * ox - 1 + kx;
      if ((unsigned)iy < (unsigned)Hin && (unsigned)ix < (unsigned)Hin)
        pix = img * (Hin * Hin) + iy * Hin + ix;
    }
    const u16* ap = &mapS[pix * 72 + kh * 8];
    bf16x8 a[4], bv[4];
#pragma unroll
    for (int kk = 0; kk < 4; ++kk) {
      a[kk]  = *(const bf16x8*)(ap + kk * 16);
      bv[kk] = *(const bf16x8*)&B2[((((kk << 1) | kh)) * 64 + bcol) * 8];
    }
#pragma unroll
    for (int kk = 0; kk < 4; ++kk)
      acc = __builtin_amdgcn_mfma_f32_32x32x16_bf16(a[kk], bv[kk], acc, 0, 0, 0);
    if (s < 8) {
      __syncthreads();   // all reads of B2 slice s complete
      *(uint4*)&B2[((c8a + 0) * 64 + bco) * 8] = nb0;
      *(uint4*)&B2[((c8a + 1) * 64 + bco) * 8] = nb1;
      __syncthreads();   // B2 slice s+1 ready
    }
  }

  // epilogue: boundary-class bias, ReLU, bf16 store, stats
  const int col = bcol;
  const int rb = m0 + 4 * (lane >> 5);
  float ls = 0.f, lss = 0.f;
#pragma unroll
  for (int r = 0; r < 16; ++r) {
    const int rw = rb + (r & 3) + 8 * (r >> 2);
    if (rw < ROWS) {
      const int re = rw / PPI, pr = rw % PPI;
      const int ooy = pr / Hout, oox = pr % Hout;
      const int ry = (ooy == 0) ? 1 : ((2 * ooy + 1 >= Hin) ? 2 : 0);
      const int rx = (oox == 0) ? 1 : ((2 * oox + 1 >= Hin) ? 2 : 0);
      const float v = fmaxf(acc[r] + biasS[(ry * 3 + rx) * 64 + col], 0.f);
      yout[((size_t)(b * 64 + e0 + re) * PPI + pr) * 64 + col] = f2bf(v);
      ls += v;
      lss = fmaf(v, v, lss);
    }
  }
  atomicAdd(&redsum[col], ls);
  atomicAdd(&redss[col], lss);
  __syncthreads();
  if (tid < 64) {
    const int sh = blk & (NSHARD - 1);
    atomicAdd(&statsSh[sh * 128 + tid], redsum[tid]);
    atomicAdd(&statsSh[sh * 128 + 64 + tid], redss[tid]);
  }
}

__global__ __launch_bounds__(256, 4) void cg2_k(
    const u16* __restrict__ yin, const u16* __restrict__ Wf,
    const float* __restrict__ biasCls, u16* __restrict__ yout,
    float* __restrict__ statsSh) {
  conv_core<14, 7, 1>(yin, Wf, biasCls, yout, statsSh, blockIdx.x);
}
__global__ __launch_bounds__(256, 4) void cg3_k(
    const u16* __restrict__ yin, const u16* __restrict__ Wf,
    const float* __restrict__ biasCls, u16* __restrict__ yout,
    float* __restrict__ statsSh) {
  conv_core<7, 4, 4>(yin, Wf, biasCls, yout, statsSh, blockIdx.x);
}
__global__ __launch_bounds__(256, 4) void cg4_k(
    const u16* __restrict__ yin, const u16* __restrict__ Wf,
    const float* __restrict__ biasCls, u16* __restrict__ yout,
    float* __restrict__ statsSh) {
  conv_core<4, 2, 16>(yin, Wf, biasCls, yout, statsSh, blockIdx.x);
}

// ---------------------------------------------------------------------------
// readout: reduce stats4 shards, feat = BN(maxpool(y4)), out = feat @ w_ro[b].
// ---------------------------------------------------------------------------
__global__ __launch_bounds__(256) void readout_k(
    const u16* __restrict__ y4, const float* __restrict__ w_ro,
    const float* __restrict__ statsSh, float invN, float* __restrict__ outp)
{
  __shared__ float wl[64 * 20];
  __shared__ float feat[64 * 64];
  __shared__ float P[256];
  __shared__ float sArr[64], tArr[64];

  const int b = blockIdx.x, tid = threadIdx.x;

  {
    const int g = tid >> 7, cidx = tid & 127;
    float acc = 0.f;
    for (int k = 0; k < NSHARD / 2; ++k)
      acc += statsSh[(g * (NSHARD / 2) + k) * 128 + cidx];
    P[tid] = acc;
  }
  for (int i = tid; i < 1280; i += 256) wl[i] = w_ro[(size_t)b * 1280 + i];
  __syncthreads();
  if (tid < 64) {
    const float m = (P[tid] + P[tid + 128]) * invN;
    const float var = fmaf(-m, m, (P[64 + tid] + P[192 + tid]) * invN);
    const float s = rsqrtf(var + BN_EPS);
    sArr[tid] = s;
    tArr[tid] = -m * s;
  }
  __syncthreads();

  {
    const int e = tid & 63;
    for (int c = tid >> 6; c < 64; c += 4) {
      const u16* p4 = y4 + ((size_t)(b * 64 + e) * 4) * 64 + c;
      const float v = fmaxf(fmaxf(bf2f(p4[0]), bf2f(p4[64])),
                            fmaxf(bf2f(p4[128]), bf2f(p4[192])));
      feat[c * 64 + e] = fmaf(v, sArr[c], tArr[c]);
    }
  }
  __syncthreads();

  const int e = tid >> 2, og = (tid & 3) * 5;
  float acc[5] = {0.f, 0.f, 0.f, 0.f, 0.f};
  for (int c = 0; c < 64; ++c) {
    const float f = feat[c * 64 + e];
#pragma unroll
    for (int j = 0; j < 5; ++j) acc[j] = fmaf(f, wl[c * 20 + og + j], acc[j]);
  }
#pragma unroll
  for (int j = 0; j < 5; ++j)
    outp[((size_t)b * 64 + e) * 20 + og + j] = acc[j];
}

// ---------------------------------------------------------------------------
extern "C" void kernel_launch(void* const* d_in, const int* in_sizes, int n_in,
                              void* d_out, int out_size, void* d_ws, size_t ws_size,
                              hipStream_t stream) {
  (void)in_sizes; (void)n_in; (void)out_size; (void)ws_size;
  const float* x   = (const float*)d_in[0];
  const float* k1  = (const float*)d_in[1];
  const float* k2  = (const float*)d_in[2];
  const float* k3  = (const float*)d_in[3];
  const float* k4  = (const float*)d_in[4];
  const float* wro = (const float*)d_in[5];
  float* out = (float*)d_out;
  char* ws = (char*)d_ws;

  // ws layout (bytes), total ~143 MB:
  //  stats: 4 layers x 64 shards x 128 f32         = 131072
  //  bias2/3/4: 64 x 576 f32                       = 3 x 147456  (memset w/ stats)
  //  k2f/k3f/k4f bf16                              = 3 x 4718592
  //  y2 bf16 [4096][49][64]                        = 25690112
  //  y1 bf16 [4096][196][64]                       = 102760448 (y3/y4 alias in)
  float* stats = (float*)ws;
  float* bias2 = (float*)(ws + 131072);
  float* bias3 = bias2 + 36864;
  float* bias4 = bias3 + 36864;
  u16* k2f = (u16*)(ws + 131072 + 442368);
  u16* k3f = k2f + (size_t)2359296;
  u16* k4f = k3f + (size_t)2359296;
  u16* y2 = k4f + (size_t)2359296;
  u16* y1 = y2 + (size_t)12845056;
  u16* y3 = y1;                      // alias: y1 dead after conv2
  u16* y4 = y3 + (size_t)4194304;

  float* st1 = stats;
  float* st2 = stats + 8192;
  float* st3 = stats + 16384;
  float* st4 = stats + 24576;

  hipMemsetAsync(stats, 0, 131072 + 442368, stream);

  conv1_k<<<4096, 256, 0, stream>>>(x, k1, y1, st1);
  foldw_k<<<192, 256, 0, stream>>>(k2, st1, 1.f / 802816.f, k2f, bias2);
  cg2_k<<<4096, 256, 0, stream>>>(y1, k2f, bias2, y2, st2);
  foldw_k<<<192, 256, 0, stream>>>(k3, st2, 1.f / 200704.f, k3f, bias3);
  cg3_k<<<1024, 256, 0, stream>>>(y2, k3f, bias3, y3, st3);
  foldw_k<<<192, 256, 0, stream>>>(k4, st3, 1.f / 65536.f, k4f, bias4);
  cg4_k<<<256, 256, 0, stream>>>(y3, k4f, bias4, y4, st4);
  readout_k<<<64, 256, 0, stream>>>(y4, wro, st4, 1.f / 16384.f, out);
}